// Round 2
// baseline (329.260 us; speedup 1.0000x reference)
//
#include <hip/hip_runtime.h>

#define K_CODES 4096
#define DIM 256
#define SEQ 2048
#define NTOK 65536

typedef __bf16 bf16x8 __attribute__((ext_vector_type(8)));
typedef float floatx4 __attribute__((ext_vector_type(4)));
typedef float floatx2 __attribute__((ext_vector_type(2)));
typedef float floatx16 __attribute__((ext_vector_type(16)));
typedef unsigned short u16x8 __attribute__((ext_vector_type(8)));

__device__ __forceinline__ unsigned short f2bf(float f) {
    union { float f; unsigned int u; } v; v.f = f;
    unsigned int u = v.u;
    unsigned int r = u + 0x7fffu + ((u >> 16) & 1u);   // RNE
    return (unsigned short)(r >> 16);
}

// async global->LDS, 16B per lane. LDS dest = wave-uniform base + lane*16.
__device__ __forceinline__ void async_cp16(const void* g, const void* lds_base) {
    typedef __attribute__((address_space(1))) const unsigned int guint;
    typedef __attribute__((address_space(3))) unsigned int luint;
    __builtin_amdgcn_global_load_lds(
        (guint*)(unsigned long long)g,
        (luint*)(unsigned int)(unsigned long long)lds_base,
        16, 0, 0);
}

// ---------------- kernel 1: codebook -> 32x32x16 B-fragment layout ----------
// For chunk gc (32 codes), K-step ks (K=16), lane = kh*32+col:
//   cb_swz[((gc*16 + ks)*64 + kh*32 + col)*8 + j]
//     = bf16(codebook[gc*32 + col][ks*16 + kh*8 + j])
// so the main loop's per-K-step read is a lane-contiguous 1KB ds_read_b128.
// norms[row] = ||e||^2 + 0.25 (bias keeps dist positive for the packed key).
__global__ __launch_bounds__(256) void k_prep(const float* __restrict__ cb,
        unsigned short* __restrict__ cb_swz, float* __restrict__ norms,
        float* __restrict__ loss_slot) {
    const int gc = blockIdx.x;        // 0..127
    const int t = threadIdx.x;
    const int colc = t >> 3;          // 0..31 code within chunk
    const int o = t & 7;              // owns k in [o*32, o*32+32)
    const int row = gc * 32 + colc;
    const float* src = cb + (size_t)row * DIM + o * 32;
    float vals[32];
    float s = 0.0f;
    #pragma unroll
    for (int i = 0; i < 8; ++i) {
        floatx4 v = *(const floatx4*)(src + i * 4);
        #pragma unroll
        for (int j = 0; j < 4; ++j) { vals[i * 4 + j] = v[j]; s += v[j] * v[j]; }
    }
    #pragma unroll
    for (int q4 = 0; q4 < 4; ++q4) {
        const int g8 = o * 4 + q4;        // global k-octet 0..31
        const int ks = g8 >> 1, kh = g8 & 1;
        u16x8 p;
        #pragma unroll
        for (int j = 0; j < 8; ++j) p[j] = f2bf(vals[q4 * 8 + j]);
        *(u16x8*)(cb_swz + ((size_t)(gc * 16 + ks) * 64 + kh * 32 + colc) * 8) = p;
    }
    s += __shfl_xor(s, 1); s += __shfl_xor(s, 2); s += __shfl_xor(s, 4);
    if (o == 0) norms[row] = s + 0.25f;
    if (gc == 0 && t == 0) *loss_slot = 0.0f;
}

// ---------------- kernel 2: MFMA distance GEMM + packed argmin --------------
// 256 thr = 4 waves, 256 tokens/block (64/wave = 2 M-tiles of 32). Codes in
// halves; twin blocks (same tokens, h=0/1) are XCD-paired via the blockIdx
// remap so their X reads share an L2. Round-0 schedule (one __syncthreads per
// chunk = minimal wait: only the 4 prior global_load_lds are outstanding),
// 2-deep ring, prefetch depth 1. 32x32x16 MFMA halves instruction count and
// runs the faster 32x32 pipe. X staging keeps the proven XOR swizzle
// (bank conflicts 7.6M -> 295K).
__global__ __launch_bounds__(256, 2) void k_argmin(const float* __restrict__ x,
        const unsigned short* __restrict__ cb_swz, const float* __restrict__ norms,
        unsigned int* __restrict__ halfmin, float* __restrict__ loss_slot) {
    __shared__ __align__(16) unsigned short xs[32 * 264];     // 16896 B
    __shared__ __align__(16) unsigned short ring[2][8192];    // 32768 B
    __shared__ __align__(16) float norms_s[2048];             //  8192 B
    __shared__ float wpart[4];
    const int t = threadIdx.x;
    const int lane = t & 63, w = t >> 6;
    const int col32 = lane & 31, kh = lane >> 5;
    // XCD pairing: twins (same tbid, h=0/1) are 8 apart in blockIdx -> same
    // XCD under round-robin dispatch. Bijection: bid <-> (tbid, h).
    const int bid = blockIdx.x;
    const int tbid = (bid & 7) * 32 + (bid >> 4);
    const int h = (bid >> 3) & 1;
    const int tb = tbid * 256;
    const int b = tb >> 11, s0 = tb & 2047;
    const float* xin = x + (size_t)b * DIM * SEQ;

    // prefetch B chunk 0 of this half into ring[0]
    {
        const char* src = (const char*)cb_swz + (size_t)h * 64 * 16384;
        #pragma unroll
        for (int i = 0; i < 4; ++i)
            async_cp16(src + i * 4096 + w * 1024 + lane * 16,
                       (char*)ring[0] + i * 4096 + w * 1024);
    }
    // norms -> LDS once
    {
        const float* ng = norms + h * 2048;
        *(floatx4*)&norms_s[t * 8]     = *(const floatx4*)(ng + t * 8);
        *(floatx4*)&norms_s[t * 8 + 4] = *(const floatx4*)(ng + t * 8 + 4);
    }

    // ---- X staging: 8 phases x 32 tokens; wave p>>1 grabs M-tile (p&1).
    // Element (tok,d) lives at xs[tok*264 + ((d>>3)^(tok>>2))*8 + (d&7)].
    bf16x8 af0[16], af1[16];
    float a2 = 0.0f;
    const int q = t & 7, dgp = t >> 3, sq = q * 4;
    #pragma unroll
    for (int p = 0; p < 8; ++p) {
        const int sbase = s0 + p * 32 + sq;
        #pragma unroll
        for (int i = 0; i < 8; ++i) {
            const int d = i * 32 + dgp;
            floatx4 v = *(const floatx4*)(xin + (size_t)d * SEQ + sbase);
            a2 += v[0]*v[0] + v[1]*v[1] + v[2]*v[2] + v[3]*v[3];
            const int chs = (d >> 3) ^ q;            // swizzled 16B chunk
            #pragma unroll
            for (int j = 0; j < 4; ++j)
                xs[(sq + j) * 264 + chs * 8 + (d & 7)] = f2bf(-2.0f * v[j]);
        }
        __syncthreads();
        if ((p >> 1) == w) {
            const int tok = col32;                   // row within 32-token slab
            const int swz = tok >> 2;
            if ((p & 1) == 0) {
                #pragma unroll
                for (int ks = 0; ks < 16; ++ks)
                    af0[ks] = *(const bf16x8*)
                        &xs[tok * 264 + ((ks * 2 + kh) ^ swz) * 8];
            } else {
                #pragma unroll
                for (int ks = 0; ks < 16; ++ks)
                    af1[ks] = *(const bf16x8*)
                        &xs[tok * 264 + ((ks * 2 + kh) ^ swz) * 8];
            }
        }
        __syncthreads();
    }
    // block-reduce a2; h==0 blocks contribute ||x||^2 part of the loss
    #pragma unroll
    for (int off = 1; off < 64; off <<= 1) a2 += __shfl_xor(a2, off);
    if (lane == 0) wpart[w] = a2;
    __syncthreads();   // also drains ring[0] prefetch on every wave
    if (t == 0 && h == 0)
        atomicAdd(loss_slot,
                  (wpart[0] + wpart[1] + wpart[2] + wpart[3]) * (1.25f / 16777216.0f));

    unsigned int minkey0[16], minkey1[16];
    #pragma unroll
    for (int r = 0; r < 16; ++r) { minkey0[r] = 0xFFFFFFFFu; minkey1[r] = 0xFFFFFFFFu; }

    #pragma unroll 1
    for (int c = 0; c < 64; ++c) {
        __syncthreads();       // ring[c&1] ready; readers of c-1 done (minimal wait)
        if (c < 63) {
            const char* srcp = (const char*)cb_swz + ((size_t)(h * 64) + c + 1) * 16384;
            char* dst = (char*)ring[(c + 1) & 1];
            #pragma unroll
            for (int i = 0; i < 4; ++i)
                async_cp16(srcp + i * 4096 + w * 1024 + lane * 16,
                           dst + i * 4096 + w * 1024);
        }
        const unsigned short* buf = ring[c & 1];
        const float nv = norms_s[c * 32 + col32];
        floatx16 acc0, acc1;
        #pragma unroll
        for (int r = 0; r < 16; ++r) { acc0[r] = nv; acc1[r] = nv; }
        #pragma unroll
        for (int hf = 0; hf < 2; ++hf) {
            bf16x8 bfr[8];
            #pragma unroll
            for (int kk = 0; kk < 8; ++kk)   // lane-contiguous 1KB: conflict-free
                bfr[kk] = *(const bf16x8*)&buf[((hf * 8 + kk) * 64 + lane) * 8];
            __builtin_amdgcn_s_setprio(1);
            #pragma unroll
            for (int kk = 0; kk < 8; ++kk) {
                acc0 = __builtin_amdgcn_mfma_f32_32x32x16_bf16(
                           af0[hf * 8 + kk], bfr[kk], acc0, 0, 0, 0);
                acc1 = __builtin_amdgcn_mfma_f32_32x32x16_bf16(
                           af1[hf * 8 + kk], bfr[kk], acc1, 0, 0, 0);
            }
            __builtin_amdgcn_s_setprio(0);
        }
        const unsigned int code = (unsigned int)((h * 64 + c) * 32) | (unsigned int)col32;
        #pragma unroll
        for (int r = 0; r < 16; ++r) {
            unsigned int k0 = (__float_as_uint(acc0[r]) & 0xFFFFF000u) | code;
            minkey0[r] = k0 < minkey0[r] ? k0 : minkey0[r];
            unsigned int k1 = (__float_as_uint(acc1[r]) & 0xFFFFF000u) | code;
            minkey1[r] = k1 < minkey1[r] ? k1 : minkey1[r];
        }
    }

    // ---- min over 32 code-lanes, write packed (dist|code) per token.
    // C layout 32x32: col=lane&31, row=(r&3)+8*(r>>2)+4*kh  [m74/m101]
    #pragma unroll
    for (int r = 0; r < 16; ++r) {
        unsigned int k = minkey0[r];
        #pragma unroll
        for (int off = 16; off >= 1; off >>= 1) {
            unsigned int o = __shfl_xor(k, off);
            k = o < k ? o : k;
        }
        if (col32 == 0)
            halfmin[h * NTOK + tb + w * 64 + (r & 3) + 8 * (r >> 2) + 4 * kh] = k;
        unsigned int k2 = minkey1[r];
        #pragma unroll
        for (int off = 16; off >= 1; off >>= 1) {
            unsigned int o = __shfl_xor(k2, off);
            k2 = o < k2 ? o : k2;
        }
        if (col32 == 0)
            halfmin[h * NTOK + tb + w * 64 + 32 + (r & 3) + 8 * (r >> 2) + 4 * kh] = k2;
    }
}

// ---------------- kernel 3: merge + LDS-staged gather + loss ----------------
// 256 thr, 64 tokens/block, two 32-token passes. Stage the gathered codebook
// rows through LDS with COALESCED reads (floatx2, 64B/row-segment per lane
// group), then transpose out of LDS (stride 258 floats: read side derived
// conflict-free, write side 4-way on 16 instrs - negligible) into coalesced
// 16B global stores.
__global__ __launch_bounds__(256) void k_gather(const float* __restrict__ cb,
        const unsigned int* __restrict__ halfmin, float* __restrict__ out,
        float* __restrict__ loss_slot) {
    __shared__ float rows_s[32 * 258];    // 33024 B
    __shared__ int sidx[64];
    const int t = threadIdx.x;
    const int tb = blockIdx.x * 64;
    const int b = tb >> 11, s0 = tb & 2047;
    if (t < 64) {
        unsigned int k0 = halfmin[tb + t], k1 = halfmin[NTOK + tb + t];
        unsigned int km = k0 < k1 ? k0 : k1;
        sidx[t] = (int)(km & 0xFFFu);
        float dv = __uint_as_float(km & 0xFFFFF000u) - 0.25f;
        #pragma unroll
        for (int off = 32; off; off >>= 1) dv += __shfl_xor(dv, off);
        if (t == 0) atomicAdd(loss_slot, dv * (1.25f / 16777216.0f));
    }
    __syncthreads();
    const int r = t >> 3, cs = (t & 7) * 32;   // stage roles: 8 thr/row
    const int qg = t & 7, dgb = t >> 3;        // write roles
    #pragma unroll 1
    for (int p = 0; p < 2; ++p) {
        if (p) __syncthreads();                // rows_s WAR between passes
        const float* srcr = cb + (size_t)sidx[p * 32 + r] * DIM + cs;
        float* dstr = &rows_s[r * 258 + cs];
        #pragma unroll
        for (int i2 = 0; i2 < 16; ++i2)
            *(floatx2*)(dstr + i2 * 2) = *(const floatx2*)(srcr + i2 * 2);
        __syncthreads();
        #pragma unroll
        for (int i = 0; i < 8; ++i) {
            const int d = i * 32 + dgb;
            floatx4 v;
            #pragma unroll
            for (int k = 0; k < 4; ++k) v[k] = rows_s[(qg * 4 + k) * 258 + d];
            *(floatx4*)(out + (size_t)b * DIM * SEQ + (size_t)d * SEQ
                        + s0 + p * 32 + qg * 4) = v;
        }
    }
}

extern "C" void kernel_launch(void* const* d_in, const int* in_sizes, int n_in,
                              void* d_out, int out_size, void* d_ws, size_t ws_size,
                              hipStream_t stream) {
    const float* inputs   = (const float*)d_in[0];
    const float* codebook = (const float*)d_in[1];
    float* out = (float*)d_out;
    unsigned short* cb_swz = (unsigned short*)d_ws;                                  // 2 MB
    float* norms = (float*)((char*)d_ws + (size_t)K_CODES * DIM * 2);                // 16 KB
    unsigned int* halfmin = (unsigned int*)((char*)d_ws + (size_t)K_CODES * DIM * 2
                                            + K_CODES * 4);                          // 512 KB
    float* loss_slot = out + (out_size - 1);

    hipLaunchKernelGGL(k_prep,   dim3(K_CODES / 32),     dim3(256), 0, stream,
                       codebook, cb_swz, norms, loss_slot);
    hipLaunchKernelGGL(k_argmin, dim3(NTOK / 256 * 2),   dim3(256), 0, stream,
                       inputs, cb_swz, norms, halfmin, loss_slot);
    hipLaunchKernelGGL(k_gather, dim3(NTOK / 64),        dim3(256), 0, stream,
                       codebook, halfmin, out, loss_slot);
}